// Round 2
// baseline (605.978 us; speedup 1.0000x reference)
//
#include <hip/hip_runtime.h>

// StreamingDurationProjector: B independent rows, each a sequential scan over U
// elements with carry (c = residual, off = prefix offset). One thread per row.
// 64-thread blocks (1 wave) -> 32 blocks spread over 32 CUs (4 per XCD).
// Register double-buffered 32-column chunks; float4/int4 vector loads per lane.

#define BUDGET_POS_F 24.0f
#define BUDGET_NEG_F 24.0f

struct Chunk {
  float4 d[8];
  int4   s[8];
  float4 m[8];
  int4   sm[8];
};

__device__ __forceinline__ void load_chunk(Chunk& ch, const float* __restrict__ dp,
                                           const int* __restrict__ sp,
                                           const float* __restrict__ mp,
                                           const int* __restrict__ smp, int base) {
#pragma unroll
  for (int i = 0; i < 8; ++i) {
    ch.d[i]  = *reinterpret_cast<const float4*>(dp + base + i * 4);
    ch.s[i]  = *reinterpret_cast<const int4*>(sp + base + i * 4);
    ch.m[i]  = *reinterpret_cast<const float4*>(mp + base + i * 4);
    ch.sm[i] = *reinterpret_cast<const int4*>(smp + base + i * 4);
  }
}

// One scan step. Exact f32 replication of the JAX reference.
__device__ __forceinline__ float step1(float d, float sf, float m, float smf,
                                       float& c, float& off) {
  float src_count = fmaxf(0.0f, rintf(sf));            // round-half-even == jnp.round
  float total     = fmaxf(0.0f, d + c);
  float frames0   = fmaxf(1.0f, floorf(total));
  float anchor    = fmaxf(1.0f, src_count);
  float lower     = fmaxf(1.0f, ceilf(anchor - (BUDGET_NEG_F + off)));
  float upper     = fmaxf(lower, floorf(anchor + (BUDGET_POS_F - off)));
  float frames    = fminf(fmaxf(frames0, lower), upper);  // jnp.clip
  bool ic  = m > 0.5f;
  bool isp = smf > 0.5f;
  bool act = ic && isp;
  float proj = ic ? (isp ? frames : src_count) : 0.0f;
  c   = act ? (total - frames) : c;
  off = act ? (off + (frames - anchor)) : off;
  return proj;
}

__device__ __forceinline__ void process_chunk(const Chunk& ch, float& c, float& off,
                                              float* __restrict__ outM,
                                              float* __restrict__ outP,
                                              float* __restrict__ outC, int base) {
#pragma unroll
  for (int i = 0; i < 8; ++i) {
    float4 dv = ch.d[i];
    int4   sv = ch.s[i];
    float4 mv = ch.m[i];
    int4   sm = ch.sm[i];
    float4 pr, pm, mt;
    pr.x = step1(dv.x, (float)sv.x, mv.x, (float)sm.x, c, off);
    pr.y = step1(dv.y, (float)sv.y, mv.y, (float)sm.y, c, off);
    pr.z = step1(dv.z, (float)sv.z, mv.z, (float)sm.z, c, off);
    pr.w = step1(dv.w, (float)sv.w, mv.w, (float)sm.w, c, off);
    pm.x = pr.x * mv.x; pm.y = pr.y * mv.y; pm.z = pr.z * mv.z; pm.w = pr.w * mv.w;
    // materialized = d + (proj*cm - d): replicate exactly (no algebraic fold).
    mt.x = dv.x + (pm.x - dv.x);
    mt.y = dv.y + (pm.y - dv.y);
    mt.z = dv.z + (pm.z - dv.z);
    mt.w = dv.w + (pm.w - dv.w);
    *reinterpret_cast<float4*>(outM + base + i * 4) = mt;
    *reinterpret_cast<float4*>(outP + base + i * 4) = pr;
    *reinterpret_cast<float4*>(outC + base + i * 4) = pm;
  }
}

__global__ __launch_bounds__(64, 1)
void sdp_scan_kernel(const float* __restrict__ dur, const int* __restrict__ src,
                     const float* __restrict__ um, const int* __restrict__ scm,
                     const float* __restrict__ res_prev,
                     const float* __restrict__ off_prev,
                     float* __restrict__ out, int B, int U) {
  int r = blockIdx.x * 64 + threadIdx.x;
  if (r >= B) return;

  float c   = res_prev[r];
  float off = rintf(off_prev[r]);

  const int tot = B * U;
  float* outM = out;                // materialized
  float* outP = out + tot;          // projected
  float* outC = out + 2 * tot;      // cached_duration_exec

  const int rowbase  = r * U;
  constexpr int CK   = 32;          // columns per chunk
  const int lastBase = tot - CK;    // clamp for the final (dead) prefetch

  int u0 = 0;
  if (U >= 2 * CK) {
    const int nPair = U / (2 * CK);
    Chunk A, Bf;
    load_chunk(A, dur, src, um, scm, rowbase);
    for (int p = 0; p < nPair; ++p) {
      const int k0 = p * 2 * CK;
      load_chunk(Bf, dur, src, um, scm, rowbase + k0 + CK);
      process_chunk(A, c, off, outM, outP, outC, rowbase + k0);
      int nb = rowbase + k0 + 2 * CK;       // next pair's first chunk
      if (nb > lastBase) nb = lastBase;     // OOB-safe dead prefetch on last pair
      load_chunk(A, dur, src, um, scm, nb);
      process_chunk(Bf, c, off, outM, outP, outC, rowbase + k0 + CK);
    }
    u0 = nPair * 2 * CK;
  }

  // Scalar tail (U % 64 != 0 safety; no-op for U = 4096).
  for (int u = u0; u < U; ++u) {
    int idx = rowbase + u;
    float pr = step1(dur[idx], (float)src[idx], um[idx], (float)scm[idx], c, off);
    float pm = pr * um[idx];
    outM[idx] = dur[idx] + (pm - dur[idx]);
    outP[idx] = pr;
    outC[idx] = pm;
  }

  out[3 * tot + r]     = c;    // residual_next
  out[3 * tot + B + r] = off;  // offset_next
}

extern "C" void kernel_launch(void* const* d_in, const int* in_sizes, int n_in,
                              void* d_out, int out_size, void* d_ws, size_t ws_size,
                              hipStream_t stream) {
  const float* dur      = (const float*)d_in[0];
  const int*   src      = (const int*)d_in[1];
  const float* um       = (const float*)d_in[2];
  const int*   scm      = (const int*)d_in[3];
  const float* res_prev = (const float*)d_in[4];
  const float* off_prev = (const float*)d_in[5];
  float* out = (float*)d_out;

  const int B = in_sizes[4];
  const int U = in_sizes[0] / B;

  dim3 grid((B + 63) / 64);
  dim3 block(64);
  sdp_scan_kernel<<<grid, block, 0, stream>>>(dur, src, um, scm, res_prev, off_prev,
                                              out, B, U);
}

// Round 3
// 526.159 us; speedup vs baseline: 1.1517x; 1.1517x over previous
//
#include <hip/hip_runtime.h>

// StreamingDurationProjector: B independent rows, each a sequential scan over U
// elements with nonlinear carry (c = residual, off = prefix offset).
// Round 3: spread rows thin -> 8 rows per wave, 256 blocks (1 per CU), so the
// per-CU memory-latency/MLP budget (~25 GB/s) is not exceeded. Lanes 8..63 idle:
// SIMD waste is free here because each wave is issue/latency-bound, not lane-bound.
// Register double-buffered 32-column chunks; float4/int4 vector loads per lane.

#define BUDGET_POS_F 24.0f
#define BUDGET_NEG_F 24.0f

#define ROWS_PER_BLOCK 8

struct Chunk {
  float4 d[8];
  int4   s[8];
  float4 m[8];
  int4   sm[8];
};

__device__ __forceinline__ void load_chunk(Chunk& ch, const float* __restrict__ dp,
                                           const int* __restrict__ sp,
                                           const float* __restrict__ mp,
                                           const int* __restrict__ smp, int base) {
#pragma unroll
  for (int i = 0; i < 8; ++i) {
    ch.d[i]  = *reinterpret_cast<const float4*>(dp + base + i * 4);
    ch.s[i]  = *reinterpret_cast<const int4*>(sp + base + i * 4);
    ch.m[i]  = *reinterpret_cast<const float4*>(mp + base + i * 4);
    ch.sm[i] = *reinterpret_cast<const int4*>(smp + base + i * 4);
  }
}

// One scan step. Exact f32 replication of the JAX reference.
__device__ __forceinline__ float step1(float d, float sf, float m, float smf,
                                       float& c, float& off) {
  float src_count = fmaxf(0.0f, rintf(sf));            // round-half-even == jnp.round
  float total     = fmaxf(0.0f, d + c);
  float frames0   = fmaxf(1.0f, floorf(total));
  float anchor    = fmaxf(1.0f, src_count);
  float lower     = fmaxf(1.0f, ceilf(anchor - (BUDGET_NEG_F + off)));
  float upper     = fmaxf(lower, floorf(anchor + (BUDGET_POS_F - off)));
  float frames    = fminf(fmaxf(frames0, lower), upper);  // jnp.clip
  bool ic  = m > 0.5f;
  bool isp = smf > 0.5f;
  bool act = ic && isp;
  float proj = ic ? (isp ? frames : src_count) : 0.0f;
  c   = act ? (total - frames) : c;
  off = act ? (off + (frames - anchor)) : off;
  return proj;
}

__device__ __forceinline__ void process_chunk(const Chunk& ch, float& c, float& off,
                                              float* __restrict__ outM,
                                              float* __restrict__ outP,
                                              float* __restrict__ outC, int base) {
#pragma unroll
  for (int i = 0; i < 8; ++i) {
    float4 dv = ch.d[i];
    int4   sv = ch.s[i];
    float4 mv = ch.m[i];
    int4   sm = ch.sm[i];
    float4 pr, pm, mt;
    pr.x = step1(dv.x, (float)sv.x, mv.x, (float)sm.x, c, off);
    pr.y = step1(dv.y, (float)sv.y, mv.y, (float)sm.y, c, off);
    pr.z = step1(dv.z, (float)sv.z, mv.z, (float)sm.z, c, off);
    pr.w = step1(dv.w, (float)sv.w, mv.w, (float)sm.w, c, off);
    pm.x = pr.x * mv.x; pm.y = pr.y * mv.y; pm.z = pr.z * mv.z; pm.w = pr.w * mv.w;
    // materialized = d + (proj*cm - d): replicate exactly (no algebraic fold).
    mt.x = dv.x + (pm.x - dv.x);
    mt.y = dv.y + (pm.y - dv.y);
    mt.z = dv.z + (pm.z - dv.z);
    mt.w = dv.w + (pm.w - dv.w);
    *reinterpret_cast<float4*>(outM + base + i * 4) = mt;
    *reinterpret_cast<float4*>(outP + base + i * 4) = pr;
    *reinterpret_cast<float4*>(outC + base + i * 4) = pm;
  }
}

__global__ __launch_bounds__(64, 1)
void sdp_scan_kernel(const float* __restrict__ dur, const int* __restrict__ src,
                     const float* __restrict__ um, const int* __restrict__ scm,
                     const float* __restrict__ res_prev,
                     const float* __restrict__ off_prev,
                     float* __restrict__ out, int B, int U) {
  // 8 rows per block: lanes 0..7 each own one row; lanes 8..63 exit.
  if (threadIdx.x >= ROWS_PER_BLOCK) return;
  int r = blockIdx.x * ROWS_PER_BLOCK + threadIdx.x;
  if (r >= B) return;

  float c   = res_prev[r];
  float off = rintf(off_prev[r]);

  const int tot = B * U;
  float* outM = out;                // materialized
  float* outP = out + tot;          // projected
  float* outC = out + 2 * tot;      // cached_duration_exec

  const int rowbase  = r * U;
  constexpr int CK   = 32;          // columns per chunk
  const int lastBase = tot - CK;    // clamp for the final (dead) prefetch

  int u0 = 0;
  if (U >= 2 * CK) {
    const int nPair = U / (2 * CK);
    Chunk A, Bf;
    load_chunk(A, dur, src, um, scm, rowbase);
    for (int p = 0; p < nPair; ++p) {
      const int k0 = p * 2 * CK;
      load_chunk(Bf, dur, src, um, scm, rowbase + k0 + CK);
      process_chunk(A, c, off, outM, outP, outC, rowbase + k0);
      int nb = rowbase + k0 + 2 * CK;       // next pair's first chunk
      if (nb > lastBase) nb = lastBase;     // OOB-safe dead prefetch on last pair
      load_chunk(A, dur, src, um, scm, nb);
      process_chunk(Bf, c, off, outM, outP, outC, rowbase + k0 + CK);
    }
    u0 = nPair * 2 * CK;
  }

  // Scalar tail (U % 64 != 0 safety; no-op for U = 4096).
  for (int u = u0; u < U; ++u) {
    int idx = rowbase + u;
    float pr = step1(dur[idx], (float)src[idx], um[idx], (float)scm[idx], c, off);
    float pm = pr * um[idx];
    outM[idx] = dur[idx] + (pm - dur[idx]);
    outP[idx] = pr;
    outC[idx] = pm;
  }

  out[3 * tot + r]     = c;    // residual_next
  out[3 * tot + B + r] = off;  // offset_next
}

extern "C" void kernel_launch(void* const* d_in, const int* in_sizes, int n_in,
                              void* d_out, int out_size, void* d_ws, size_t ws_size,
                              hipStream_t stream) {
  const float* dur      = (const float*)d_in[0];
  const int*   src      = (const int*)d_in[1];
  const float* um       = (const float*)d_in[2];
  const int*   scm      = (const int*)d_in[3];
  const float* res_prev = (const float*)d_in[4];
  const float* off_prev = (const float*)d_in[5];
  float* out = (float*)d_out;

  const int B = in_sizes[4];
  const int U = in_sizes[0] / B;

  dim3 grid((B + ROWS_PER_BLOCK - 1) / ROWS_PER_BLOCK);
  dim3 block(64);
  sdp_scan_kernel<<<grid, block, 0, stream>>>(dur, src, um, scm, res_prev, off_prev,
                                              out, B, U);
}